// Round 1
// baseline (321.679 us; speedup 1.0000x reference)
//
#include <hip/hip_runtime.h>

// Bicubic (Catmull-Rom) warped interpolation.
// input: img [B,C,H,W] fp32, delta_x [B,C,H,W], delta_y [B,C,H,W]
// out:   [B,C,H,W] fp32, clipped to [0,1]
// H = W = 1024 (hardcoded; power-of-two index math).

#define HD 1024
#define WD 1024

__global__ __launch_bounds__(256) void bicubic_warp_kernel(
    const float* __restrict__ img,
    const float* __restrict__ dxp,
    const float* __restrict__ dyp,
    float* __restrict__ out,
    int total)
{
    int idx = blockIdx.x * blockDim.x + threadIdx.x;
    if (idx >= total) return;

    const int x     = idx & (WD - 1);
    const int y     = (idx >> 10) & (HD - 1);
    const int plane = idx >> 20;
    const float* __restrict__ p = img + (size_t)plane * (size_t)(HD * WD);

    const float ddx = dxp[idx];
    const float ddy = dyp[idx];

    // Mirror reference math:
    // new = (coord + d - N/2) / (N/2 - 1); map = (new + 1) * (N-1)/2
    const float invWm = 1.0f / (WD * 0.5f - 1.0f);   // 1/511
    const float invHm = 1.0f / (HD * 0.5f - 1.0f);
    float newX = ((float)x + ddx - WD * 0.5f) * invWm;
    float newY = ((float)y + ddy - HD * 0.5f) * invHm;
    float x_map = (newX + 1.0f) * ((WD - 1) * 0.5f); // * 511.5
    float y_map = (newY + 1.0f) * ((HD - 1) * 0.5f);

    float x0f = floorf(x_map);
    float y0f = floorf(y_map);
    float tx = x_map - x0f;
    float ty = y_map - y0f;
    int x0 = (int)x0f;
    int y0 = (int)y0f;

    // Catmull-Rom weights
    float tx2 = tx * tx, tx3 = tx2 * tx;
    float wxm1 = (-tx3 + 2.0f * tx2 - tx) * 0.5f;
    float wx0  = (3.0f * tx3 - 5.0f * tx2 + 2.0f) * 0.5f;
    float wx1  = (-3.0f * tx3 + 4.0f * tx2 + tx) * 0.5f;
    float wx2  = 1.0f - (wxm1 + wx0 + wx1);

    float ty2 = ty * ty, ty3 = ty2 * ty;
    float wym1 = (-ty3 + 2.0f * ty2 - ty) * 0.5f;
    float wy0  = (3.0f * ty3 - 5.0f * ty2 + 2.0f) * 0.5f;
    float wy1  = (-3.0f * ty3 + 4.0f * ty2 + ty) * 0.5f;
    float wy2  = 1.0f - (wym1 + wy0 + wy1);

    // clamped tap indices
    int xs0 = min(max(x0 - 1, 0), WD - 1);
    int xs1 = min(max(x0,     0), WD - 1);
    int xs2 = min(max(x0 + 1, 0), WD - 1);
    int xs3 = min(max(x0 + 2, 0), WD - 1);
    int ys0 = min(max(y0 - 1, 0), HD - 1);
    int ys1 = min(max(y0,     0), HD - 1);
    int ys2 = min(max(y0 + 1, 0), HD - 1);
    int ys3 = min(max(y0 + 2, 0), HD - 1);

    float acc = 0.0f;
    {
        const float* __restrict__ r = p + (size_t)ys0 * WD;
        float row = wxm1 * r[xs0] + wx0 * r[xs1] + wx1 * r[xs2] + wx2 * r[xs3];
        acc = fmaf(wym1, row, acc);
    }
    {
        const float* __restrict__ r = p + (size_t)ys1 * WD;
        float row = wxm1 * r[xs0] + wx0 * r[xs1] + wx1 * r[xs2] + wx2 * r[xs3];
        acc = fmaf(wy0, row, acc);
    }
    {
        const float* __restrict__ r = p + (size_t)ys2 * WD;
        float row = wxm1 * r[xs0] + wx0 * r[xs1] + wx1 * r[xs2] + wx2 * r[xs3];
        acc = fmaf(wy1, row, acc);
    }
    {
        const float* __restrict__ r = p + (size_t)ys3 * WD;
        float row = wxm1 * r[xs0] + wx0 * r[xs1] + wx1 * r[xs2] + wx2 * r[xs3];
        acc = fmaf(wy2, row, acc);
    }

    out[idx] = fminf(fmaxf(acc, 0.0f), 1.0f);
}

extern "C" void kernel_launch(void* const* d_in, const int* in_sizes, int n_in,
                              void* d_out, int out_size, void* d_ws, size_t ws_size,
                              hipStream_t stream) {
    const float* img = (const float*)d_in[0];
    const float* dxp = (const float*)d_in[1];
    const float* dyp = (const float*)d_in[2];
    float* out = (float*)d_out;

    int total = in_sizes[0];
    int block = 256;
    int grid = (total + block - 1) / block;
    bicubic_warp_kernel<<<grid, block, 0, stream>>>(img, dxp, dyp, out, total);
}

// Round 2
// 113.263 us; speedup vs baseline: 2.8401x; 2.8401x over previous
//
#include <hip/hip_runtime.h>

// Bicubic (Catmull-Rom) warped interpolation, LDS-tiled.
// img/delta_x/delta_y: [B,C,H,W] fp32; out: [B,C,H,W] fp32 clipped to [0,1].
// H = W = 1024. Tile: 64x64 output per 256-thread block, staged 84x84 in LDS
// (halo = 8 covers |delta| up to ~7; out-of-tile taps take a global fallback).

#define HD 1024
#define WD 1024
#define TILE 64
#define HALO 8
#define SW 84   // staged width/height = TILE + 2*HALO + 4 (tap window slack)

__device__ __forceinline__ float cubic_gather_global(
    const float* __restrict__ p, int x0, int y0,
    float wxm1, float wx0, float wx1, float wx2,
    float wym1, float wy0, float wy1, float wy2)
{
    int cx0 = min(max(x0 - 1, 0), WD - 1);
    int cx1 = min(max(x0,     0), WD - 1);
    int cx2 = min(max(x0 + 1, 0), WD - 1);
    int cx3 = min(max(x0 + 2, 0), WD - 1);
    int cy0 = min(max(y0 - 1, 0), HD - 1);
    int cy1 = min(max(y0,     0), HD - 1);
    int cy2 = min(max(y0 + 1, 0), HD - 1);
    int cy3 = min(max(y0 + 2, 0), HD - 1);
    const float* r0 = p + (size_t)cy0 * WD;
    const float* r1 = p + (size_t)cy1 * WD;
    const float* r2 = p + (size_t)cy2 * WD;
    const float* r3 = p + (size_t)cy3 * WD;
    float s0 = wxm1 * r0[cx0] + wx0 * r0[cx1] + wx1 * r0[cx2] + wx2 * r0[cx3];
    float s1 = wxm1 * r1[cx0] + wx0 * r1[cx1] + wx1 * r1[cx2] + wx2 * r1[cx3];
    float s2 = wxm1 * r2[cx0] + wx0 * r2[cx1] + wx1 * r2[cx2] + wx2 * r2[cx3];
    float s3 = wxm1 * r3[cx0] + wx0 * r3[cx1] + wx1 * r3[cx2] + wx2 * r3[cx3];
    return wym1 * s0 + wy0 * s1 + wy1 * s2 + wy2 * s3;
}

__global__ __launch_bounds__(256) void bicubic_tile_kernel(
    const float* __restrict__ img,
    const float* __restrict__ dxp,
    const float* __restrict__ dyp,
    float* __restrict__ out)
{
    __shared__ float sm[SW * SW];

    const int bx = blockIdx.x * TILE;
    const int by = blockIdx.y * TILE;
    const int plane = blockIdx.z;
    const float* __restrict__ p = img + (size_t)plane * (size_t)(HD * WD);

    const int gx0 = bx - HALO;
    const int gy0 = by - HALO;
    const int tid = threadIdx.x;

    // ---- stage [gy0, gy0+SW) x [gx0, gx0+SW) into LDS (edge-clamped) ----
    if (gx0 >= 0 && gx0 + SW <= WD) {
        // interior in x: vectorized float4 staging (gx0 is a multiple of 4)
        #pragma unroll
        for (int it = 0; it < (SW * (SW / 4) + 255) / 256; ++it) {
            int s = tid + it * 256;
            if (s < SW * (SW / 4)) {
                int row = s / (SW / 4);
                int q = s - row * (SW / 4);
                int gy = min(max(gy0 + row, 0), HD - 1);
                float4 v = *reinterpret_cast<const float4*>(p + (size_t)gy * WD + gx0 + 4 * q);
                *reinterpret_cast<float4*>(&sm[row * SW + 4 * q]) = v;
            }
        }
    } else {
        // x-edge tile: scalar staging with clamp
        for (int s = tid; s < SW * SW; s += 256) {
            int row = s / SW;
            int col = s - row * SW;
            int gy = min(max(gy0 + row, 0), HD - 1);
            int gx = min(max(gx0 + col, 0), WD - 1);
            sm[row * SW + col] = p[(size_t)gy * WD + gx];
        }
    }
    __syncthreads();

    // ---- compute: each thread does 4 consecutive x, 4 row-iterations ----
    const int xq = (tid & 15) * 4;  // local x of this thread's quad
    const int yb = tid >> 4;        // 0..15

    for (int r = 0; r < 4; ++r) {
        const int ly = yb + 16 * r;
        const int y = by + ly;
        const int xg = bx + xq;
        const int didx = (plane << 20) | (y << 10) | xg;

        const float4 dx4 = *reinterpret_cast<const float4*>(dxp + didx);
        const float4 dy4 = *reinterpret_cast<const float4*>(dyp + didx);
        float res[4];

        #pragma unroll
        for (int k = 0; k < 4; ++k) {
            const int x = xg + k;
            const float ddx = (&dx4.x)[k];
            const float ddy = (&dy4.x)[k];

            // same op order as reference
            float newX = ((float)x + ddx - WD * 0.5f) * (1.0f / (WD * 0.5f - 1.0f));
            float newY = ((float)y + ddy - HD * 0.5f) * (1.0f / (HD * 0.5f - 1.0f));
            float x_map = (newX + 1.0f) * ((WD - 1) * 0.5f);
            float y_map = (newY + 1.0f) * ((HD - 1) * 0.5f);

            float x0f = floorf(x_map);
            float y0f = floorf(y_map);
            float tx = x_map - x0f;
            float ty = y_map - y0f;
            int x0 = (int)x0f;
            int y0 = (int)y0f;

            float tx2 = tx * tx, tx3 = tx2 * tx;
            float wxm1 = (-tx3 + 2.0f * tx2 - tx) * 0.5f;
            float wx0  = (3.0f * tx3 - 5.0f * tx2 + 2.0f) * 0.5f;
            float wx1  = (-3.0f * tx3 + 4.0f * tx2 + tx) * 0.5f;
            float wx2  = 1.0f - (wxm1 + wx0 + wx1);

            float ty2 = ty * ty, ty3 = ty2 * ty;
            float wym1 = (-ty3 + 2.0f * ty2 - ty) * 0.5f;
            float wy0  = (3.0f * ty3 - 5.0f * ty2 + 2.0f) * 0.5f;
            float wy1  = (-3.0f * ty3 + 4.0f * ty2 + ty) * 0.5f;
            float wy2  = 1.0f - (wym1 + wy0 + wy1);

            int cx0 = min(max(x0 - 1, 0), WD - 1);
            int cx1 = min(max(x0,     0), WD - 1);
            int cx2 = min(max(x0 + 1, 0), WD - 1);
            int cx3 = min(max(x0 + 2, 0), WD - 1);
            int cy0 = min(max(y0 - 1, 0), HD - 1);
            int cy1 = min(max(y0,     0), HD - 1);
            int cy2 = min(max(y0 + 1, 0), HD - 1);
            int cy3 = min(max(y0 + 2, 0), HD - 1);

            bool inb = (cx0 >= gx0) && (cx3 <= gx0 + SW - 1) &&
                       (cy0 >= gy0) && (cy3 <= gy0 + SW - 1);

            float acc;
            if (inb) {
                int lx0 = cx0 - gx0, lx1 = cx1 - gx0, lx2 = cx2 - gx0, lx3 = cx3 - gx0;
                int lb0 = (cy0 - gy0) * SW;
                int lb1 = (cy1 - gy0) * SW;
                int lb2 = (cy2 - gy0) * SW;
                int lb3 = (cy3 - gy0) * SW;
                float s0 = wxm1 * sm[lb0 + lx0] + wx0 * sm[lb0 + lx1] + wx1 * sm[lb0 + lx2] + wx2 * sm[lb0 + lx3];
                float s1 = wxm1 * sm[lb1 + lx0] + wx0 * sm[lb1 + lx1] + wx1 * sm[lb1 + lx2] + wx2 * sm[lb1 + lx3];
                float s2 = wxm1 * sm[lb2 + lx0] + wx0 * sm[lb2 + lx1] + wx1 * sm[lb2 + lx2] + wx2 * sm[lb2 + lx3];
                float s3 = wxm1 * sm[lb3 + lx0] + wx0 * sm[lb3 + lx1] + wx1 * sm[lb3 + lx2] + wx2 * sm[lb3 + lx3];
                acc = wym1 * s0 + wy0 * s1 + wy1 * s2 + wy2 * s3;
            } else {
                acc = cubic_gather_global(p, x0, y0, wxm1, wx0, wx1, wx2,
                                          wym1, wy0, wy1, wy2);
            }
            res[k] = fminf(fmaxf(acc, 0.0f), 1.0f);
        }

        float4 o;
        o.x = res[0]; o.y = res[1]; o.z = res[2]; o.w = res[3];
        *reinterpret_cast<float4*>(out + didx) = o;
    }
}

extern "C" void kernel_launch(void* const* d_in, const int* in_sizes, int n_in,
                              void* d_out, int out_size, void* d_ws, size_t ws_size,
                              hipStream_t stream) {
    const float* img = (const float*)d_in[0];
    const float* dxp = (const float*)d_in[1];
    const float* dyp = (const float*)d_in[2];
    float* out = (float*)d_out;

    const int planes = in_sizes[0] / (HD * WD);  // B*C = 24
    dim3 grid(WD / TILE, HD / TILE, planes);
    bicubic_tile_kernel<<<grid, 256, 0, stream>>>(img, dxp, dyp, out);
}

// Round 3
// 108.855 us; speedup vs baseline: 2.9551x; 1.0405x over previous
//
#include <hip/hip_runtime.h>

// Bicubic (Catmull-Rom) warped interpolation, LDS-tiled, conflict-free mapping.
// img/delta_x/delta_y: [B,C,H,W] fp32; out: [B,C,H,W] fp32 clipped to [0,1].
// H = W = 1024. Tile: 64x64 output per 256-thread block; 80x80 image patch
// staged in LDS (stride 84: 16B-aligned, ==20 mod 32 so cross-row divergence
// scatters banks). Lane = column (stride-1 across lanes -> 2 lanes/bank, free).
// Out-of-patch taps (|delta| > ~5) take a rare global-gather fallback.

#define HD 1024
#define WD 1024
#define TILE 64
#define HALO 8
#define SROWS 80   // staged rows & cols of valid data
#define SSTR 84    // LDS row stride in floats (84*4 bytes, 16B-aligned)

__device__ __forceinline__ float cubic_gather_global(
    const float* __restrict__ p, int x0, int y0,
    float wxm1, float wx0, float wx1, float wx2,
    float wym1, float wy0, float wy1, float wy2)
{
    int cx0 = min(max(x0 - 1, 0), WD - 1);
    int cx1 = min(max(x0,     0), WD - 1);
    int cx2 = min(max(x0 + 1, 0), WD - 1);
    int cx3 = min(max(x0 + 2, 0), WD - 1);
    int cy0 = min(max(y0 - 1, 0), HD - 1);
    int cy1 = min(max(y0,     0), HD - 1);
    int cy2 = min(max(y0 + 1, 0), HD - 1);
    int cy3 = min(max(y0 + 2, 0), HD - 1);
    const float* r0 = p + (size_t)cy0 * WD;
    const float* r1 = p + (size_t)cy1 * WD;
    const float* r2 = p + (size_t)cy2 * WD;
    const float* r3 = p + (size_t)cy3 * WD;
    float s0 = wxm1 * r0[cx0] + wx0 * r0[cx1] + wx1 * r0[cx2] + wx2 * r0[cx3];
    float s1 = wxm1 * r1[cx0] + wx0 * r1[cx1] + wx1 * r1[cx2] + wx2 * r1[cx3];
    float s2 = wxm1 * r2[cx0] + wx0 * r2[cx1] + wx1 * r2[cx2] + wx2 * r2[cx3];
    float s3 = wxm1 * r3[cx0] + wx0 * r3[cx1] + wx1 * r3[cx2] + wx2 * r3[cx3];
    return wym1 * s0 + wy0 * s1 + wy1 * s2 + wy2 * s3;
}

__global__ __launch_bounds__(256) void bicubic_tile_kernel(
    const float* __restrict__ img,
    const float* __restrict__ dxp,
    const float* __restrict__ dyp,
    float* __restrict__ out)
{
    __shared__ float sm[SROWS * SSTR];

    const int bx = blockIdx.x * TILE;
    const int by = blockIdx.y * TILE;
    const int plane = blockIdx.z;
    const float* __restrict__ p = img + (size_t)plane * (size_t)(HD * WD);

    const int gx0 = bx - HALO;
    const int gy0 = by - HALO;
    const int tid = threadIdx.x;

    // ---- stage 80 rows x 80 cols of [gy0, gx0] patch into LDS (edge-clamped)
    if (gx0 >= 0 && gx0 + SROWS <= WD) {
        // interior in x: vectorized float4 staging (gx0 is 4-aligned)
        for (int s = tid; s < SROWS * (SROWS / 4); s += 256) {
            int r = s / (SROWS / 4);
            int q = s - r * (SROWS / 4);
            int gy = min(max(gy0 + r, 0), HD - 1);
            float4 v = *reinterpret_cast<const float4*>(p + (size_t)gy * WD + gx0 + 4 * q);
            *reinterpret_cast<float4*>(&sm[r * SSTR + 4 * q]) = v;
        }
    } else {
        // x-edge tile: scalar staging with clamp
        for (int s = tid; s < SROWS * SROWS; s += 256) {
            int r = s / SROWS;
            int c = s - r * SROWS;
            int gy = min(max(gy0 + r, 0), HD - 1);
            int gx = min(max(gx0 + c, 0), WD - 1);
            sm[r * SSTR + c] = p[(size_t)gy * WD + gx];
        }
    }
    __syncthreads();

    // ---- compute: lane = column (64 consecutive cols per wave), 16 rows/thread
    const int col = bx + (tid & 63);
    const int rbase = by + (tid >> 6);

    #pragma unroll 4
    for (int it = 0; it < 16; ++it) {
        const int y = rbase + it * 4;
        const int didx = (plane << 20) | (y << 10) | col;

        const float ddx = dxp[didx];
        const float ddy = dyp[didx];

        // same op order as reference
        float newX = ((float)col + ddx - WD * 0.5f) * (1.0f / (WD * 0.5f - 1.0f));
        float newY = ((float)y   + ddy - HD * 0.5f) * (1.0f / (HD * 0.5f - 1.0f));
        float x_map = (newX + 1.0f) * ((WD - 1) * 0.5f);
        float y_map = (newY + 1.0f) * ((HD - 1) * 0.5f);

        float x0f = floorf(x_map);
        float y0f = floorf(y_map);
        float tx = x_map - x0f;
        float ty = y_map - y0f;
        int x0 = (int)x0f;
        int y0 = (int)y0f;

        float tx2 = tx * tx, tx3 = tx2 * tx;
        float wxm1 = (-tx3 + 2.0f * tx2 - tx) * 0.5f;
        float wx0  = (3.0f * tx3 - 5.0f * tx2 + 2.0f) * 0.5f;
        float wx1  = (-3.0f * tx3 + 4.0f * tx2 + tx) * 0.5f;
        float wx2  = 1.0f - (wxm1 + wx0 + wx1);

        float ty2 = ty * ty, ty3 = ty2 * ty;
        float wym1 = (-ty3 + 2.0f * ty2 - ty) * 0.5f;
        float wy0  = (3.0f * ty3 - 5.0f * ty2 + 2.0f) * 0.5f;
        float wy1  = (-3.0f * ty3 + 4.0f * ty2 + ty) * 0.5f;
        float wy2  = 1.0f - (wym1 + wy0 + wy1);

        // raw tap window (no clamps needed: LDS holds edge-clamped values)
        const int lx = x0 - 1 - gx0;
        const int ly = y0 - 1 - gy0;
        const bool inb = (lx >= 0) & (lx <= SROWS - 4) & (ly >= 0) & (ly <= SROWS - 4);

        float acc;
        if (inb) {
            const float* b = &sm[ly * SSTR + lx];
            float s0 = wxm1 * b[0 * SSTR + 0] + wx0 * b[0 * SSTR + 1] + wx1 * b[0 * SSTR + 2] + wx2 * b[0 * SSTR + 3];
            float s1 = wxm1 * b[1 * SSTR + 0] + wx0 * b[1 * SSTR + 1] + wx1 * b[1 * SSTR + 2] + wx2 * b[1 * SSTR + 3];
            float s2 = wxm1 * b[2 * SSTR + 0] + wx0 * b[2 * SSTR + 1] + wx1 * b[2 * SSTR + 2] + wx2 * b[2 * SSTR + 3];
            float s3 = wxm1 * b[3 * SSTR + 0] + wx0 * b[3 * SSTR + 1] + wx1 * b[3 * SSTR + 2] + wx2 * b[3 * SSTR + 3];
            acc = wym1 * s0 + wy0 * s1 + wy1 * s2 + wy2 * s3;
        } else {
            acc = cubic_gather_global(p, x0, y0, wxm1, wx0, wx1, wx2,
                                      wym1, wy0, wy1, wy2);
        }
        out[didx] = fminf(fmaxf(acc, 0.0f), 1.0f);
    }
}

extern "C" void kernel_launch(void* const* d_in, const int* in_sizes, int n_in,
                              void* d_out, int out_size, void* d_ws, size_t ws_size,
                              hipStream_t stream) {
    const float* img = (const float*)d_in[0];
    const float* dxp = (const float*)d_in[1];
    const float* dyp = (const float*)d_in[2];
    float* out = (float*)d_out;

    const int planes = in_sizes[0] / (HD * WD);  // B*C = 24
    dim3 grid(WD / TILE, HD / TILE, planes);
    bicubic_tile_kernel<<<grid, 256, 0, stream>>>(img, dxp, dyp, out);
}